// Round 12
// baseline (959.277 us; speedup 1.0000x reference)
//
#include <hip/hip_runtime.h>
#include <hip/hip_bf16.h>

// GCN: 3x GraphConv(norm='both') + 4->2 linear + softmax.
// Round 12: src-major streamed push. The dst-side random gather is pinned at
// ~176us/layer by the XCD fabric random-line-request ceiling (~2.4 req/cy/XCD,
// invariant to occupancy/MLP/L1-bypass/L2-hit-rate - rounds 4-11). Replace it:
//  - Sort edges once by src-coarse bucket: SP=(src_local<<20)|dst (runs ~1KB).
//  - Per layer, scatter: stage the bucket's 4096-node H slice in LDS (64KB,
//    SEQUENTIAL load), stream (value,dst_local) into dst-coarse-partitioned
//    runs (245 streams/block, rankC-proven write pattern).
//  - Accumulate: per dst-coarse bucket, read the value segment SEQUENTIALLY
//    into a 64KB LDS acc (4096 dsts), apply the existing fused epilogues.
// All hot-path traffic becomes streaming (~380MB/layer @ ~6TB/s).
// Fallback: round-9 path if ws_size < ~222MB; round-2 path below that.

#define BT 256
#define BTL 1024
#define LOGW 9
#define NPB 512
#define LOGC 12
#define CNPB 4096
#define KCMAX 256
#define CH 65536
#define NBIN 64
#define SEC 5               // sections per src-coarse bucket in scatter phase

// ================= round-12 src-major streamed path =================

// hist of src-coarse buckets over original edges -> M2 (column-major [KC][NBLK])
__global__ void histS_kernel(const int* __restrict__ src, int* __restrict__ M2,
                             int E, int KC, int NBLK) {
    __shared__ int h2[KCMAX];
    for (int l = threadIdx.x; l < KC; l += BTL) h2[l] = 0;
    __syncthreads();
    int base = blockIdx.x * CH;
    int lim = min(E - base, CH);
    for (int j = threadIdx.x; j < lim; j += BTL)
        atomicAdd(&h2[src[base + j] >> LOGC], 1);
    __syncthreads();
    for (int l = threadIdx.x; l < KC; l += BTL)
        M2[(size_t)l * NBLK + blockIdx.x] = h2[l];
}

// one wave per row: exclusive scan along columns (in place), row total out
__global__ void rowscan1_kernel(int* __restrict__ M, int* __restrict__ bsum, int NCOL) {
    int b = blockIdx.x, lane = threadIdx.x;
    size_t rb = (size_t)b * NCOL;
    int carry = 0;
    for (int base = 0; base < NCOL; base += 64) {
        int idx = base + lane;
        int v = (idx < NCOL) ? M[rb + idx] : 0;
        int s = v;
        #pragma unroll
        for (int o = 1; o < 64; o <<= 1) { int u = __shfl_up(s, o); if (lane >= o) s += u; }
        if (idx < NCOL) M[rb + idx] = carry + s - v;
        carry += __shfl(s, 63);
    }
    if (lane == 0) bsum[b] = carry;
}

// single block, 256 threads: exclusive scan of totals (K <= 256) -> base[K+1]
__global__ void scan1_kernel(const int* __restrict__ bs, int* __restrict__ base, int K) {
    __shared__ int wt[4];
    int t = threadIdx.x, lane = t & 63, w = t >> 6;
    int v = (t < K) ? bs[t] : 0;
    int s = v;
    #pragma unroll
    for (int o = 1; o < 64; o <<= 1) { int u = __shfl_up(s, o); if (lane >= o) s += u; }
    if (lane == 63) wt[w] = s;
    __syncthreads();
    int wpre = 0;
    for (int j = 0; j < w; ++j) wpre += wt[j];
    if (t < K) base[t] = wpre + s - v;
    if (t == 255) base[K] = wpre + s;
}

// scatter edges into src-coarse buckets: SP = (src_local<<20)|dst (unsigned)
__global__ void rankS_kernel(const int* __restrict__ src, const int* __restrict__ dst,
                             const int* __restrict__ M2, const int* __restrict__ cb2,
                             unsigned int* __restrict__ SP, int E, int KC, int NBLK) {
    __shared__ int c2[KCMAX];
    int blk = blockIdx.x;
    for (int l = threadIdx.x; l < KC; l += BTL)
        c2[l] = cb2[l] + M2[(size_t)l * NBLK + blk];
    __syncthreads();
    int base = blk * CH;
    int lim = min(E - base, CH);
    for (int j = threadIdx.x; j < lim; j += BTL) {
        int s = src[base + j], d = dst[base + j];
        int q = atomicAdd(&c2[s >> LOGC], 1);
        SP[q] = ((unsigned int)(s & (CNPB - 1)) << 20) | (unsigned int)d;
    }
}

// out-degrees per src-coarse bucket -> ns, sx
__global__ void sdegS_kernel(const unsigned int* __restrict__ SP, const int* __restrict__ cb2,
                             const float* __restrict__ x,
                             float* __restrict__ ns, float* __restrict__ sx, int N) {
    __shared__ int h[CNPB];
    int b = blockIdx.x;
    for (int l = threadIdx.x; l < CNPB; l += BTL) h[l] = 0;
    __syncthreads();
    int gb = cb2[b], ge = cb2[b + 1];
    for (int j = gb + threadIdx.x; j < ge; j += BTL) atomicAdd(&h[SP[j] >> 20], 1);
    __syncthreads();
    int vb = b << LOGC;
    for (int l = threadIdx.x; l < CNPB; l += BTL) {
        int v = vb + l;
        if (v < N) {
            int d = h[l];
            float nsv = d > 0 ? rsqrtf((float)d) : 0.f;
            ns[v] = nsv;
            sx[v] = x[v] * nsv;
        }
    }
}

// hist of dst-coarse bins per (src-bucket,section) -> MF [KD][NS]
__global__ void histF_kernel(const unsigned int* __restrict__ SP, const int* __restrict__ cb2,
                             int* __restrict__ MF, int KD, int NS) {
    __shared__ int h[KCMAX];
    int col = blockIdx.x;
    int b = col / SEC, sec = col % SEC;
    for (int l = threadIdx.x; l < KD; l += BTL) h[l] = 0;
    __syncthreads();
    int gb = cb2[b], ge = cb2[b + 1];
    int len = (ge - gb + SEC - 1) / SEC;
    int s0 = gb + sec * len, s1 = min(s0 + len, ge);
    for (int j = s0 + threadIdx.x; j < s1; j += BTL)
        atomicAdd(&h[(SP[j] & 0xFFFFFu) >> LOGC], 1);
    __syncthreads();
    for (int l = threadIdx.x; l < KD; l += BTL)
        MF[(size_t)l * NS + col] = h[l];
}

// layer-1 scatter: LDS tile of sx (scalar), stream (value,dst_local) to dst-coarse runs
__global__ void scat1_kernel(const unsigned int* __restrict__ SP, const int* __restrict__ cb2,
                             const int* __restrict__ MF, const int* __restrict__ fbase,
                             const float* __restrict__ sx,
                             float* __restrict__ EV1, unsigned short* __restrict__ DL,
                             int KD, int NS, int N) {
    __shared__ float tile[CNPB];
    __shared__ int cur[KCMAX];
    int col = blockIdx.x;
    int b = col / SEC, sec = col % SEC;
    for (int l = threadIdx.x; l < KD; l += BTL)
        cur[l] = fbase[l] + MF[(size_t)l * NS + col];
    int sb = b << LOGC;
    for (int idx = threadIdx.x; idx < CNPB; idx += BTL) {
        int g = sb + idx;
        tile[idx] = (g < N) ? sx[g] : 0.f;
    }
    __syncthreads();
    int gb = cb2[b], ge = cb2[b + 1];
    int len = (ge - gb + SEC - 1) / SEC;
    int s0 = gb + sec * len, s1 = min(s0 + len, ge);
    for (int j = s0 + threadIdx.x; j < s1; j += BTL) {
        unsigned int v = SP[j];
        float h = tile[v >> 20];
        int kd = (int)((v & 0xFFFFFu) >> LOGC);
        int p = atomicAdd(&cur[kd], 1);
        EV1[p] = h;
        DL[p] = (unsigned short)(v & (CNPB - 1));
    }
}

// layer-1 accumulate: per dst-coarse bucket, LDS acc + cnt -> nd + epilogue + W2 -> A
__global__ void acc1_kernel(const float* __restrict__ EV1, const unsigned short* __restrict__ DL,
                            const int* __restrict__ fbase,
                            const float* __restrict__ ns, float* __restrict__ nd,
                            const float* __restrict__ W1, const float* __restrict__ b1,
                            const float* __restrict__ W2, float4* __restrict__ A, int N) {
    __shared__ float acc[CNPB];
    __shared__ int cnt[CNPB];
    int k = blockIdx.x;
    for (int l = threadIdx.x; l < CNPB; l += BTL) { acc[l] = 0.f; cnt[l] = 0; }
    __syncthreads();
    int gb = fbase[k], ge = fbase[k + 1];
    for (int j = gb + threadIdx.x; j < ge; j += BTL) {
        int l = DL[j];
        atomicAdd(&acc[l], EV1[j]);
        atomicAdd(&cnt[l], 1);
    }
    __syncthreads();
    int vb = k << LOGC;
    for (int l = threadIdx.x; l < CNPB; l += BTL) {
        int v = vb + l;
        if (v < N) {
            int hh = cnt[l];
            float ndv = hh > 0 ? rsqrtf((float)hh) : 0.f;
            nd[v] = ndv;
            float tt = acc[l] * ndv;
            float nsv = ns[v];
            float x0 = fmaxf(tt * W1[0] + b1[0], 0.f) * nsv;
            float x1 = fmaxf(tt * W1[1] + b1[1], 0.f) * nsv;
            float x2 = fmaxf(tt * W1[2] + b1[2], 0.f) * nsv;
            float x3 = fmaxf(tt * W1[3] + b1[3], 0.f) * nsv;
            float4 o;
            o.x = x0*W2[0] + x1*W2[4] + x2*W2[8]  + x3*W2[12];
            o.y = x0*W2[1] + x1*W2[5] + x2*W2[9]  + x3*W2[13];
            o.z = x0*W2[2] + x1*W2[6] + x2*W2[10] + x3*W2[14];
            o.w = x0*W2[3] + x1*W2[7] + x2*W2[11] + x3*W2[15];
            A[v] = o;
        }
    }
}

// layers 2/3 scatter: LDS tile of H (float4, 64KB), stream float4 values
__global__ void scat4_kernel(const unsigned int* __restrict__ SP, const int* __restrict__ cb2,
                             const int* __restrict__ MF, const int* __restrict__ fbase,
                             const float4* __restrict__ H,
                             float4* __restrict__ EV, unsigned short* __restrict__ DL,
                             int KD, int NS, int N) {
    __shared__ float4 tile[CNPB];
    __shared__ int cur[KCMAX];
    int col = blockIdx.x;
    int b = col / SEC, sec = col % SEC;
    for (int l = threadIdx.x; l < KD; l += BTL)
        cur[l] = fbase[l] + MF[(size_t)l * NS + col];
    int sb = b << LOGC;
    for (int idx = threadIdx.x; idx < CNPB; idx += BTL) {
        int g = sb + idx;
        tile[idx] = (g < N) ? H[g] : make_float4(0.f, 0.f, 0.f, 0.f);
    }
    __syncthreads();
    int gb = cb2[b], ge = cb2[b + 1];
    int len = (ge - gb + SEC - 1) / SEC;
    int s0 = gb + sec * len, s1 = min(s0 + len, ge);
    for (int j = s0 + threadIdx.x; j < s1; j += BTL) {
        unsigned int v = SP[j];
        float4 h = tile[v >> 20];
        int kd = (int)((v & 0xFFFFFu) >> LOGC);
        int p = atomicAdd(&cur[kd], 1);
        EV[p] = h;
        DL[p] = (unsigned short)(v & (CNPB - 1));
    }
}

// middle accumulate: LDS acc[4096*4] + g4 epilogue -> out
__global__ void acc4_kernel(const float4* __restrict__ EV, const unsigned short* __restrict__ DL,
                            const int* __restrict__ fbase,
                            const float* __restrict__ ns, const float* __restrict__ nd,
                            const float* __restrict__ bb, const float* __restrict__ W,
                            float4* __restrict__ out, int N) {
    __shared__ float acc[CNPB * 4];
    int k = blockIdx.x;
    for (int l = threadIdx.x; l < CNPB * 4; l += BTL) acc[l] = 0.f;
    __syncthreads();
    int gb = fbase[k], ge = fbase[k + 1];
    for (int j = gb + threadIdx.x; j < ge; j += BTL) {
        float4 v = EV[j];
        int l4 = (int)DL[j] * 4;
        atomicAdd(&acc[l4 + 0], v.x);
        atomicAdd(&acc[l4 + 1], v.y);
        atomicAdd(&acc[l4 + 2], v.z);
        atomicAdd(&acc[l4 + 3], v.w);
    }
    __syncthreads();
    int vb = k << LOGC;
    for (int l = threadIdx.x; l < CNPB; l += BTL) {
        int v = vb + l;
        if (v < N) {
            float ndv = nd[v], nsv = ns[v];
            float x0 = fmaxf(acc[l*4+0] * ndv + bb[0], 0.f) * nsv;
            float x1 = fmaxf(acc[l*4+1] * ndv + bb[1], 0.f) * nsv;
            float x2 = fmaxf(acc[l*4+2] * ndv + bb[2], 0.f) * nsv;
            float x3 = fmaxf(acc[l*4+3] * ndv + bb[3], 0.f) * nsv;
            float4 o;
            o.x = x0*W[0] + x1*W[4] + x2*W[8]  + x3*W[12];
            o.y = x0*W[1] + x1*W[5] + x2*W[9]  + x3*W[13];
            o.z = x0*W[2] + x1*W[6] + x2*W[10] + x3*W[14];
            o.w = x0*W[3] + x1*W[7] + x2*W[11] + x3*W[15];
            out[v] = o;
        }
    }
}

// final accumulate: epilogue (no relu) + [4,2] linear + softmax -> out
__global__ void accF_kernel(const float4* __restrict__ EV, const unsigned short* __restrict__ DL,
                            const int* __restrict__ fbase, const float* __restrict__ nd,
                            const float* __restrict__ bb, const float* __restrict__ Wl,
                            const float* __restrict__ bl, float2* __restrict__ out, int N) {
    __shared__ float acc[CNPB * 4];
    int k = blockIdx.x;
    for (int l = threadIdx.x; l < CNPB * 4; l += BTL) acc[l] = 0.f;
    __syncthreads();
    int gb = fbase[k], ge = fbase[k + 1];
    for (int j = gb + threadIdx.x; j < ge; j += BTL) {
        float4 v = EV[j];
        int l4 = (int)DL[j] * 4;
        atomicAdd(&acc[l4 + 0], v.x);
        atomicAdd(&acc[l4 + 1], v.y);
        atomicAdd(&acc[l4 + 2], v.z);
        atomicAdd(&acc[l4 + 3], v.w);
    }
    __syncthreads();
    int vb = k << LOGC;
    for (int l = threadIdx.x; l < CNPB; l += BTL) {
        int v = vb + l;
        if (v < N) {
            float ndv = nd[v];
            float x0 = acc[l*4+0] * ndv + bb[0];
            float x1 = acc[l*4+1] * ndv + bb[1];
            float x2 = acc[l*4+2] * ndv + bb[2];
            float x3 = acc[l*4+3] * ndv + bb[3];
            float z0 = x0*Wl[0] + x1*Wl[2] + x2*Wl[4] + x3*Wl[6] + bl[0];
            float z1 = x0*Wl[1] + x1*Wl[3] + x2*Wl[5] + x3*Wl[7] + bl[1];
            float m  = fmaxf(z0, z1);
            float e0 = expf(z0 - m), e1 = expf(z1 - m);
            float inv = 1.f / (e0 + e1);
            out[v] = make_float2(e0 * inv, e1 * inv);
        }
    }
}

// ================= round-9 fallback (dst-gather path) =================

__global__ void histC_kernel(const int* __restrict__ src, const int* __restrict__ dst,
                             int* __restrict__ M1, int* __restrict__ M2,
                             int E, int KC, int NBLK) {
    __shared__ int h1[KCMAX];
    __shared__ int h2[KCMAX];
    for (int l = threadIdx.x; l < KC; l += BTL) { h1[l] = 0; h2[l] = 0; }
    __syncthreads();
    int base = blockIdx.x * CH;
    int lim = min(E - base, CH);
    for (int j = threadIdx.x; j < lim; j += BTL) {
        atomicAdd(&h1[dst[base + j] >> LOGC], 1);
        atomicAdd(&h2[src[base + j] >> LOGC], 1);
    }
    __syncthreads();
    for (int l = threadIdx.x; l < KC; l += BTL) {
        M1[(size_t)l * NBLK + blockIdx.x] = h1[l];
        M2[(size_t)l * NBLK + blockIdx.x] = h2[l];
    }
}

__global__ void rowscan_kernel(int* __restrict__ M1, int* __restrict__ M2,
                               int* __restrict__ bsum1, int* __restrict__ bsum2, int NBLK) {
    int b = blockIdx.x, lane = threadIdx.x;
    size_t rb = (size_t)b * NBLK;
    int carry = 0;
    for (int base = 0; base < NBLK; base += 64) {
        int idx = base + lane;
        int v = (idx < NBLK) ? M1[rb + idx] : 0;
        int s = v;
        #pragma unroll
        for (int o = 1; o < 64; o <<= 1) { int u = __shfl_up(s, o); if (lane >= o) s += u; }
        if (idx < NBLK) M1[rb + idx] = carry + s - v;
        carry += __shfl(s, 63);
    }
    if (lane == 0) bsum1[b] = carry;
    carry = 0;
    for (int base = 0; base < NBLK; base += 64) {
        int idx = base + lane;
        int v = (idx < NBLK) ? M2[rb + idx] : 0;
        int s = v;
        #pragma unroll
        for (int o = 1; o < 64; o <<= 1) { int u = __shfl_up(s, o); if (lane >= o) s += u; }
        if (idx < NBLK) M2[rb + idx] = carry + s - v;
        carry += __shfl(s, 63);
    }
    if (lane == 0) bsum2[b] = carry;
}

__global__ void scanC_kernel(const int* __restrict__ bs1, int* __restrict__ cb1,
                             const int* __restrict__ bs2, int* __restrict__ cb2,
                             int* __restrict__ bbase1, int KC) {
    __shared__ int wt[4];
    int t = threadIdx.x, lane = t & 63, w = t >> 6;
    int v = (t < KC) ? bs1[t] : 0;
    int s = v;
    #pragma unroll
    for (int o = 1; o < 64; o <<= 1) { int u = __shfl_up(s, o); if (lane >= o) s += u; }
    if (lane == 63) wt[w] = s;
    __syncthreads();
    int wpre = 0;
    for (int j = 0; j < w; ++j) wpre += wt[j];
    if (t < KC) cb1[t] = wpre + s - v;
    if (t == 255) { int tot = wpre + s; cb1[KC] = tot; bbase1[8 * KC] = tot; }
    __syncthreads();
    v = (t < KC) ? bs2[t] : 0;
    s = v;
    #pragma unroll
    for (int o = 1; o < 64; o <<= 1) { int u = __shfl_up(s, o); if (lane >= o) s += u; }
    if (lane == 63) wt[w] = s;
    __syncthreads();
    wpre = 0;
    for (int j = 0; j < w; ++j) wpre += wt[j];
    if (t < KC) cb2[t] = wpre + s - v;
    if (t == 255) cb2[KC] = wpre + s;
}

__global__ void rankC_kernel(const int* __restrict__ src, const int* __restrict__ dst,
                             const int* __restrict__ M1, const int* __restrict__ M2,
                             const int* __restrict__ cb1, const int* __restrict__ cb2,
                             unsigned int* __restrict__ PC, int* __restrict__ SC,
                             int E, int KC, int NBLK) {
    __shared__ int c1[KCMAX];
    __shared__ int c2[KCMAX];
    int blk = blockIdx.x;
    for (int l = threadIdx.x; l < KC; l += BTL) {
        c1[l] = cb1[l] + M1[(size_t)l * NBLK + blk];
        c2[l] = cb2[l] + M2[(size_t)l * NBLK + blk];
    }
    __syncthreads();
    int base = blk * CH;
    int lim = min(E - base, CH);
    for (int j = threadIdx.x; j < lim; j += BTL) {
        int s = src[base + j], d = dst[base + j];
        int p = atomicAdd(&c1[d >> LOGC], 1);
        PC[p] = ((unsigned int)s << LOGC) | (unsigned int)(d & (CNPB - 1));
        int q = atomicAdd(&c2[s >> LOGC], 1);
        SC[q] = s;
    }
}

__global__ void sdegC_kernel(const int* __restrict__ SC, const int* __restrict__ cb2,
                             const float* __restrict__ x,
                             float* __restrict__ ns, float* __restrict__ sx, int N) {
    __shared__ int h[CNPB];
    int b = blockIdx.x;
    for (int l = threadIdx.x; l < CNPB; l += BTL) h[l] = 0;
    __syncthreads();
    int gb = cb2[b], ge = cb2[b + 1];
    for (int j = gb + threadIdx.x; j < ge; j += BTL) atomicAdd(&h[SC[j] & (CNPB - 1)], 1);
    __syncthreads();
    int vb = b << LOGC;
    for (int l = threadIdx.x; l < CNPB; l += BTL) {
        int v = vb + l;
        if (v < N) {
            int d = h[l];
            float nsv = d > 0 ? rsqrtf((float)d) : 0.f;
            ns[v] = nsv;
            sx[v] = x[v] * nsv;
        }
    }
}

__global__ void fine_kernel(const unsigned int* __restrict__ PC, const int* __restrict__ cb1,
                            unsigned int* __restrict__ P, int* __restrict__ bbase1) {
    __shared__ int h[NBIN];
    __shared__ int cur[NBIN];
    int b = blockIdx.x;
    int gb = cb1[b], ge = cb1[b + 1];
    int t = threadIdx.x;
    if (t < NBIN) h[t] = 0;
    __syncthreads();
    for (int j = gb + t; j < ge; j += BTL) {
        unsigned int val = PC[j];
        int bin = (int)(((val >> LOGW) & 7u) << 3) | (int)(val >> 29);
        atomicAdd(&h[bin], 1);
    }
    __syncthreads();
    if (t < 64) {
        int v = h[t];
        int s = v;
        #pragma unroll
        for (int o = 1; o < 64; o <<= 1) { int u = __shfl_up(s, o); if (t >= o) s += u; }
        int excl = s - v;
        cur[t] = gb + excl;
        if ((t & 7) == 0) bbase1[b * 8 + (t >> 3)] = gb + excl;
    }
    __syncthreads();
    for (int j = gb + t; j < ge; j += BTL) {
        unsigned int val = PC[j];
        int bin = (int)(((val >> LOGW) & 7u) << 3) | (int)(val >> 29);
        int p = atomicAdd(&cur[bin], 1);
        P[p] = ((val >> LOGC) << LOGW) | (val & (NPB - 1));
    }
}

__global__ void g1_kernel(const unsigned int* __restrict__ P, const int* __restrict__ bbase1,
                          const float* __restrict__ sx, const float* __restrict__ ns,
                          float* __restrict__ nd,
                          const float* __restrict__ W1, const float* __restrict__ b1,
                          const float* __restrict__ W2, float4* __restrict__ A, int N) {
    __shared__ float acc[NPB];
    __shared__ int cnt[NPB];
    int b = blockIdx.x;
    for (int l = threadIdx.x; l < NPB; l += BT) { acc[l] = 0.f; cnt[l] = 0; }
    __syncthreads();
    int gb = bbase1[b], ge = bbase1[b + 1];
    for (int j = gb + threadIdx.x; j < ge; j += BT) {
        unsigned int val = P[j];
        int l = (int)(val & (NPB - 1));
        atomicAdd(&acc[l], sx[val >> LOGW]);
        atomicAdd(&cnt[l], 1);
    }
    __syncthreads();
    int vb = b << LOGW;
    for (int l = threadIdx.x; l < NPB; l += BT) {
        int v = vb + l;
        if (v < N) {
            int hh = cnt[l];
            float ndv = hh > 0 ? rsqrtf((float)hh) : 0.f;
            nd[v] = ndv;
            float tt = acc[l] * ndv;
            float nsv = ns[v];
            float x0 = fmaxf(tt * W1[0] + b1[0], 0.f) * nsv;
            float x1 = fmaxf(tt * W1[1] + b1[1], 0.f) * nsv;
            float x2 = fmaxf(tt * W1[2] + b1[2], 0.f) * nsv;
            float x3 = fmaxf(tt * W1[3] + b1[3], 0.f) * nsv;
            float4 o;
            o.x = x0*W2[0] + x1*W2[4] + x2*W2[8]  + x3*W2[12];
            o.y = x0*W2[1] + x1*W2[5] + x2*W2[9]  + x3*W2[13];
            o.z = x0*W2[2] + x1*W2[6] + x2*W2[10] + x3*W2[14];
            o.w = x0*W2[3] + x1*W2[7] + x2*W2[11] + x3*W2[15];
            A[v] = o;
        }
    }
}

__global__ void g4_kernel(const unsigned int* __restrict__ P, const int* __restrict__ bbase1,
                          const float4* __restrict__ H, const float* __restrict__ ns,
                          const float* __restrict__ nd,
                          const float* __restrict__ bb, const float* __restrict__ W,
                          float4* __restrict__ out, int N) {
    __shared__ float acc[NPB * 4];
    int b = blockIdx.x;
    for (int l = threadIdx.x; l < NPB * 4; l += BT) acc[l] = 0.f;
    __syncthreads();
    int gb = bbase1[b], ge = bbase1[b + 1];
    for (int j = gb + threadIdx.x; j < ge; j += BT) {
        unsigned int val = P[j];
        float4 v = H[val >> LOGW];
        int l4 = (int)(val & (NPB - 1)) * 4;
        atomicAdd(&acc[l4 + 0], v.x);
        atomicAdd(&acc[l4 + 1], v.y);
        atomicAdd(&acc[l4 + 2], v.z);
        atomicAdd(&acc[l4 + 3], v.w);
    }
    __syncthreads();
    int vb = b << LOGW;
    for (int l = threadIdx.x; l < NPB; l += BT) {
        int v = vb + l;
        if (v < N) {
            float ndv = nd[v], nsv = ns[v];
            float x0 = fmaxf(acc[l*4+0] * ndv + bb[0], 0.f) * nsv;
            float x1 = fmaxf(acc[l*4+1] * ndv + bb[1], 0.f) * nsv;
            float x2 = fmaxf(acc[l*4+2] * ndv + bb[2], 0.f) * nsv;
            float x3 = fmaxf(acc[l*4+3] * ndv + bb[3], 0.f) * nsv;
            float4 o;
            o.x = x0*W[0] + x1*W[4] + x2*W[8]  + x3*W[12];
            o.y = x0*W[1] + x1*W[5] + x2*W[9]  + x3*W[13];
            o.z = x0*W[2] + x1*W[6] + x2*W[10] + x3*W[14];
            o.w = x0*W[3] + x1*W[7] + x2*W[11] + x3*W[15];
            out[v] = o;
        }
    }
}

__global__ void gF_kernel(const unsigned int* __restrict__ P, const int* __restrict__ bbase1,
                          const float4* __restrict__ H, const float* __restrict__ nd,
                          const float* __restrict__ bb, const float* __restrict__ Wl,
                          const float* __restrict__ bl, float2* __restrict__ out, int N) {
    __shared__ float acc[NPB * 4];
    int b = blockIdx.x;
    for (int l = threadIdx.x; l < NPB * 4; l += BT) acc[l] = 0.f;
    __syncthreads();
    int gb = bbase1[b], ge = bbase1[b + 1];
    for (int j = gb + threadIdx.x; j < ge; j += BT) {
        unsigned int val = P[j];
        float4 v = H[val >> LOGW];
        int l4 = (int)(val & (NPB - 1)) * 4;
        atomicAdd(&acc[l4 + 0], v.x);
        atomicAdd(&acc[l4 + 1], v.y);
        atomicAdd(&acc[l4 + 2], v.z);
        atomicAdd(&acc[l4 + 3], v.w);
    }
    __syncthreads();
    int vb = b << LOGW;
    for (int l = threadIdx.x; l < NPB; l += BT) {
        int v = vb + l;
        if (v < N) {
            float ndv = nd[v];
            float x0 = acc[l*4+0] * ndv + bb[0];
            float x1 = acc[l*4+1] * ndv + bb[1];
            float x2 = acc[l*4+2] * ndv + bb[2];
            float x3 = acc[l*4+3] * ndv + bb[3];
            float z0 = x0*Wl[0] + x1*Wl[2] + x2*Wl[4] + x3*Wl[6] + bl[0];
            float z1 = x0*Wl[1] + x1*Wl[3] + x2*Wl[5] + x3*Wl[7] + bl[1];
            float m  = fmaxf(z0, z1);
            float e0 = expf(z0 - m), e1 = expf(z1 - m);
            float inv = 1.f / (e0 + e1);
            out[v] = make_float2(e0 * inv, e1 * inv);
        }
    }
}

extern "C" void kernel_launch(void* const* d_in, const int* in_sizes, int n_in,
                              void* d_out, int out_size, void* d_ws, size_t ws_size,
                              hipStream_t stream) {
    const float* in_feat = (const float*)d_in[0];
    const int*   src     = (const int*)d_in[1];
    const int*   dst     = (const int*)d_in[2];
    const float* W1 = (const float*)d_in[3];
    const float* b1 = (const float*)d_in[4];
    const float* W2 = (const float*)d_in[5];
    const float* b2 = (const float*)d_in[6];
    const float* W3 = (const float*)d_in[7];
    const float* b3 = (const float*)d_in[8];
    const float* Wl = (const float*)d_in[9];
    const float* bl = (const float*)d_in[10];

    const int N = in_sizes[0];
    const int E = in_sizes[1];

    const int KC   = (N + CNPB - 1) >> LOGC;     // coarse buckets (src & dst)
    const int NBLK = (E + CH - 1) / CH;
    const int NS   = KC * SEC;                   // scatter sections
    const size_t uN = (size_t)N, uE = (size_t)E;

    // ---------- round-12 src-major streamed path ----------
    // units: ns|nd|sx (3N) | CT(1100) | M2(KC*NBLK) | MF(KC*NS) | SP(E)
    //        | DL((E+1)/2) | EV(4E) | A(4N) | B(4N)
    {
        const size_t CT = 1100;
        const size_t szM2 = (size_t)KC * NBLK;
        const size_t szMF = (size_t)KC * NS;
        const size_t need12 = (3 * uN + CT + szM2 + szMF + uE + (uE + 1) / 2
                               + 4 * uE + 8 * uN) * 4;
        if (ws_size >= need12 && N <= (1 << 20) && KC <= KCMAX) {
            float* ws   = (float*)d_ws;
            float* ns   = ws;
            float* nd   = ws + uN;
            float* sx   = ws + 2 * uN;
            int*   ctr  = (int*)(ws + 3 * uN);
            int* bs2    = ctr;            // KC totals
            int* cb2    = ctr + 260;      // KC+1 bases (src-coarse)
            int* bsF    = ctr + 520;      // KD totals
            int* fbase  = ctr + 780;      // KD+1 bases (dst-coarse value runs)
            int*   M2   = (int*)(ws + 3 * uN + CT);
            int*   MF   = M2 + szM2;
            unsigned int* SP = (unsigned int*)(MF + szMF);
            unsigned short* DL = (unsigned short*)(SP + uE);
            float* EV   = (float*)(SP + uE + (uE + 1) / 2);
            float4* EV4 = (float4*)EV;
            float4* A   = (float4*)(EV + 4 * uE);
            float4* B4  = A + uN;

            histS_kernel<<<NBLK, BTL, 0, stream>>>(src, M2, E, KC, NBLK);
            rowscan1_kernel<<<KC, 64, 0, stream>>>(M2, bs2, NBLK);
            scan1_kernel<<<1, 256, 0, stream>>>(bs2, cb2, KC);
            rankS_kernel<<<NBLK, BTL, 0, stream>>>(src, dst, M2, cb2, SP, E, KC, NBLK);
            sdegS_kernel<<<KC, BTL, 0, stream>>>(SP, cb2, in_feat, ns, sx, N);
            histF_kernel<<<NS, BTL, 0, stream>>>(SP, cb2, MF, KC, NS);
            rowscan1_kernel<<<KC, 64, 0, stream>>>(MF, bsF, NS);
            scan1_kernel<<<1, 256, 0, stream>>>(bsF, fbase, KC);
            // layer 1
            scat1_kernel<<<NS, BTL, 0, stream>>>(SP, cb2, MF, fbase, sx, EV, DL, KC, NS, N);
            acc1_kernel<<<KC, BTL, 0, stream>>>(EV, DL, fbase, ns, nd, W1, b1, W2, A, N);
            // layer 2
            scat4_kernel<<<NS, BTL, 0, stream>>>(SP, cb2, MF, fbase, A, EV4, DL, KC, NS, N);
            acc4_kernel<<<KC, BTL, 0, stream>>>(EV4, DL, fbase, ns, nd, b2, W3, B4, N);
            // layer 3
            scat4_kernel<<<NS, BTL, 0, stream>>>(SP, cb2, MF, fbase, B4, EV4, DL, KC, NS, N);
            accF_kernel<<<KC, BTL, 0, stream>>>(EV4, DL, fbase, nd, b3, Wl, bl, (float2*)d_out, N);
            return;
        }
    }

    // ---------- round-9 fallback (dst-gather path) ----------
    const int K = (N + NPB - 1) >> LOGW;
    const size_t CTRI = 257 * 4 + 8 * (size_t)KCMAX + 8;
    const size_t r1 = (uE > 8 * uN) ? uE : 8 * uN;
    const size_t need9 = (3 * uN + CTRI + r1 + uE) * 4;
    const bool ok9 = (ws_size >= need9) && (N <= (1 << 20)) && (KC <= KCMAX)
                     && (2 * (size_t)KC * NBLK <= uN);
    if (ok9) {
        float* ws   = (float*)d_ws;
        float* ns   = ws;
        float* nd   = ws + uN;
        float* sx   = ws + 2 * uN;
        int*   ctr  = (int*)(ws + 3 * uN);
        int* bs1    = ctr;
        int* bs2    = ctr + 257;
        int* cb1    = ctr + 514;
        int* cb2    = ctr + 771;
        int* bbase1 = ctr + 1028;
        int*   R1   = (int*)(ws + 3 * uN + CTRI);
        int*   R2   = R1 + r1;
        int*   M1   = (int*)nd;
        int*   M2   = M1 + (size_t)KC * NBLK;
        unsigned int* PC = (unsigned int*)R1;
        int*   SC   = R2;
        unsigned int* P  = (unsigned int*)R2;
        float4* A   = (float4*)R1;
        float4* B4  = (float4*)(R1 + 4 * uN);

        histC_kernel<<<NBLK, BTL, 0, stream>>>(src, dst, M1, M2, E, KC, NBLK);
        rowscan_kernel<<<KC, 64, 0, stream>>>(M1, M2, bs1, bs2, NBLK);
        scanC_kernel<<<1, 256, 0, stream>>>(bs1, cb1, bs2, cb2, bbase1, KC);
        rankC_kernel<<<NBLK, BTL, 0, stream>>>(src, dst, M1, M2, cb1, cb2, PC, SC, E, KC, NBLK);
        sdegC_kernel<<<KC, BTL, 0, stream>>>(SC, cb2, in_feat, ns, sx, N);
        fine_kernel<<<KC, BTL, 0, stream>>>(PC, cb1, P, bbase1);
        g1_kernel<<<K, BT, 0, stream>>>(P, bbase1, sx, ns, nd, W1, b1, W2, A, N);
        g4_kernel<<<K, BT, 0, stream>>>(P, bbase1, A, ns, nd, b2, W3, B4, N);
        gF_kernel<<<K, BT, 0, stream>>>(P, bbase1, B4, nd, b3, Wl, bl, (float2*)d_out, N);
    }
}